// Round 1
// baseline (168.422 us; speedup 1.0000x reference)
//
#include <hip/hip_runtime.h>
#include <stdint.h>

typedef unsigned int  uint32;
typedef unsigned short ushort16;
typedef unsigned long long u64;

#define L2E 1.44269504088896340736f

typedef float f32x4 __attribute__((ext_vector_type(4)));
typedef short bf16x8 __attribute__((ext_vector_type(8)));

__device__ __forceinline__ unsigned short f2bf(float f){
  uint32 u = __float_as_uint(f);
  u += 0x7fffu + ((u >> 16) & 1u);
  return (unsigned short)(u >> 16);
}

// ---------------- K1: h[row][o] = dot(x[row][:], W[o][:])  (fp32) ----------------
__global__ __launch_bounds__(256) void k_h(const float* __restrict__ x,
                                           const float* __restrict__ W,
                                           float* __restrict__ h){
  __shared__ float Wl[128 * 257];
  __shared__ float xl[16 * 256];
  const int tid = threadIdx.x;
  for (int idx = tid; idx < 8192; idx += 256){
    float4 v = ((const float4*)W)[idx];
    int o = idx >> 6, f = (idx & 63) * 4;
    float* d = &Wl[o * 257 + f];
    d[0] = v.x; d[1] = v.y; d[2] = v.z; d[3] = v.w;
  }
  const int row0 = blockIdx.x * 16;
  for (int idx = tid; idx < 1024; idx += 256){
    int r = idx >> 6, f = (idx & 63) * 4;
    float4 v = *(const float4*)(x + (size_t)(row0 + r) * 256 + f);
    *(float4*)&xl[r * 256 + f] = v;
  }
  __syncthreads();
  const int o = tid & 127, half = tid >> 7;
  float acc[8] = {0,0,0,0,0,0,0,0};
  for (int f = 0; f < 256; f += 4){
    float w0 = Wl[o*257+f], w1 = Wl[o*257+f+1], w2 = Wl[o*257+f+2], w3 = Wl[o*257+f+3];
    #pragma unroll
    for (int r = 0; r < 8; ++r){
      const float* xr = &xl[(half*8 + r) * 256 + f];
      acc[r] = fmaf(xr[0], w0, fmaf(xr[1], w1, fmaf(xr[2], w2, fmaf(xr[3], w3, acc[r]))));
    }
  }
  #pragma unroll
  for (int r = 0; r < 8; ++r)
    h[(size_t)(row0 + half*8 + r) * 128 + o] = acc[r];
}

// ---------------- K1b: E1 = (h.a1)*L2E ; E2 = (h.a2 + ab)*L2E ----------------
__global__ __launch_bounds__(256) void k_sv(const float* __restrict__ h,
                                            const float* __restrict__ a1,
                                            const float* __restrict__ a2,
                                            const float* __restrict__ ab,
                                            float* __restrict__ E1,
                                            float* __restrict__ E2){
  const int row  = blockIdx.x * 4 + (threadIdx.x >> 6);
  const int lane = threadIdx.x & 63;
  float2 v = *(const float2*)(h + (size_t)row * 128 + lane * 2);
  float p1 = v.x * a1[lane*2] + v.y * a1[lane*2+1];
  float p2 = v.x * a2[lane*2] + v.y * a2[lane*2+1];
  #pragma unroll
  for (int off = 32; off; off >>= 1){
    p1 += __shfl_down(p1, off);
    p2 += __shfl_down(p2, off);
  }
  if (lane == 0){
    E1[row] = p1 * L2E;
    E2[row] = (p2 + ab[0]) * L2E;
  }
}

// ---------------- K2: denom_j = sum_i adj_ij * exp(lrelu(.)) ; adjacency bitmask ----------------
__global__ __launch_bounds__(256) void k_dm(const float* __restrict__ adj,
                                            const float* __restrict__ E1,
                                            const float* __restrict__ E2,
                                            float* __restrict__ denom,
                                            u64* __restrict__ mask){
  const int b  = blockIdx.z, jt = blockIdx.x, ic = blockIdx.y;
  const int wv = threadIdx.x >> 6, lane = threadIdx.x & 63;
  const int j  = jt * 64 + lane;
  const int i0 = (ic * 4 + wv) * 128;
  const float e2 = E2[b * 2048 + j];
  const float* ap  = adj + (size_t)(b * 2048 + i0) * 2048 + j;
  const float* e1p = E1 + b * 2048 + i0;
  u64* mp = mask + (size_t)(b * 2048 + i0) * 32 + jt;
  float dsum = 0.f;
  for (int ii = 0; ii < 128; ++ii){
    float av = ap[(size_t)ii * 2048];
    float t  = e1p[ii] + e2;
    t = fmaxf(t, 0.2f * t);
    float w = av * exp2f(t);     // av ∈ {0,1} exactly
    dsum += w;
    u64 blt = __ballot(av != 0.f);
    if (lane == 0) mp[ii * 32] = blt;
  }
  atomicAdd(&denom[b * 2048 + j], dsum);
}

// ---------------- K3: gT[b][o][j] = bf16( h[b][j][o] / denom[b][j] ) ----------------
__global__ __launch_bounds__(256) void k_gt(const float* __restrict__ h,
                                            const float* __restrict__ denom,
                                            unsigned short* __restrict__ gT){
  __shared__ unsigned short tl[32][33];
  const int b = blockIdx.z;
  const int j0 = blockIdx.x * 32, o0 = blockIdx.y * 32;
  {
    const int tj = threadIdx.x >> 3, tf = threadIdx.x & 7;
    int row = b * 2048 + j0 + tj;
    float rec = 1.0f / denom[row];
    float4 v = *(const float4*)(h + (size_t)row * 128 + o0 + tf * 4);
    tl[tj][tf*4+0] = f2bf(v.x * rec);
    tl[tj][tf*4+1] = f2bf(v.y * rec);
    tl[tj][tf*4+2] = f2bf(v.z * rec);
    tl[tj][tf*4+3] = f2bf(v.w * rec);
  }
  __syncthreads();
  {
    const int to = threadIdx.x >> 3, jf = threadIdx.x & 7;
    int o = o0 + to;
    ushort4 u;
    u.x = tl[jf*4+0][to];
    u.y = tl[jf*4+1][to];
    u.z = tl[jf*4+2][to];
    u.w = tl[jf*4+3][to];
    *(ushort4*)(gT + (size_t)(b * 128 + o) * 2048 + j0 + jf * 4) = u;
  }
}

// ---------------- K4: out = ELU( A @ g ), A synthesized from E1/E2/mask ----------------
// A-frag (16x16x32 bf16): lane l holds A[row = l&15][k = 8*(l>>4)+e], e=0..7
// B-frag:                 lane l holds B[k = 8*(l>>4)+e][col = l&15]
// D:                      lane l, reg q -> row = (l>>4)*4+q, col = l&15   (m89-verified)
__global__ __launch_bounds__(256) void k_main(const float* __restrict__ E1,
                                              const float* __restrict__ E2,
                                              const uint32* __restrict__ mask32,
                                              const unsigned short* __restrict__ gT,
                                              float* __restrict__ out){
  __shared__ float cmb[4][32][129];
  const int b  = blockIdx.y;
  const int ib = blockIdx.x;                 // 32-row i-block
  const int wv = threadIdx.x >> 6, lane = threadIdx.x & 63;
  const int r  = lane & 15, kg = lane >> 4;
  const int gi0 = b * 2048 + ib * 32 + r;    // si=0 row (global)
  const float e1_0 = E1[gi0];
  const float e1_1 = E1[gi0 + 16];
  const uint32* m0 = mask32 + (size_t)gi0 * 64;
  const uint32* m1 = mask32 + (size_t)(gi0 + 16) * 64;
  const unsigned short* gbase = gT + (size_t)(b * 128) * 2048;

  f32x4 acc[2][8];
  #pragma unroll
  for (int si = 0; si < 2; ++si)
    #pragma unroll
    for (int so = 0; so < 8; ++so)
      acc[si][so] = (f32x4){0.f, 0.f, 0.f, 0.f};

  const int k0 = wv * 512, k1 = k0 + 512;
  for (int kk = k0; kk < k1; kk += 32){
    const int j0 = kk + kg * 8;
    const float4 eA = *(const float4*)(E2 + b * 2048 + j0);
    const float4 eB = *(const float4*)(E2 + b * 2048 + j0 + 4);
    const uint32 bits0 = (m0[kk >> 5] >> (kg * 8)) & 0xffu;
    const uint32 bits1 = (m1[kk >> 5] >> (kg * 8)) & 0xffu;
    float e2v[8] = {eA.x, eA.y, eA.z, eA.w, eB.x, eB.y, eB.z, eB.w};

    union { uint32 u[4]; bf16x8 v; } af0, af1;
    #pragma unroll
    for (int p = 0; p < 4; ++p){
      // si = 0
      {
        float t0 = e1_0 + e2v[2*p];     t0 = fmaxf(t0, 0.2f * t0);
        float t1 = e1_0 + e2v[2*p+1];   t1 = fmaxf(t1, 0.2f * t1);
        float x0 = ((bits0 >> (2*p))   & 1u) ? exp2f(t0) : 0.f;
        float x1 = ((bits0 >> (2*p+1)) & 1u) ? exp2f(t1) : 0.f;
        uint32 u0 = __float_as_uint(x0); u0 = (u0 + 0x7fffu + ((u0 >> 16) & 1u)) >> 16;
        uint32 u1 = __float_as_uint(x1); u1 = (u1 + 0x7fffu + ((u1 >> 16) & 1u)) & 0xffff0000u;
        af0.u[p] = u0 | u1;
      }
      // si = 1
      {
        float t0 = e1_1 + e2v[2*p];     t0 = fmaxf(t0, 0.2f * t0);
        float t1 = e1_1 + e2v[2*p+1];   t1 = fmaxf(t1, 0.2f * t1);
        float x0 = ((bits1 >> (2*p))   & 1u) ? exp2f(t0) : 0.f;
        float x1 = ((bits1 >> (2*p+1)) & 1u) ? exp2f(t1) : 0.f;
        uint32 u0 = __float_as_uint(x0); u0 = (u0 + 0x7fffu + ((u0 >> 16) & 1u)) >> 16;
        uint32 u1 = __float_as_uint(x1); u1 = (u1 + 0x7fffu + ((u1 >> 16) & 1u)) & 0xffff0000u;
        af1.u[p] = u0 | u1;
      }
    }
    #pragma unroll
    for (int so = 0; so < 8; ++so){
      const int o = so * 16 + r;
      bf16x8 bfr = *(const bf16x8*)(gbase + (size_t)o * 2048 + j0);
      acc[0][so] = __builtin_amdgcn_mfma_f32_16x16x32_bf16(af0.v, bfr, acc[0][so], 0, 0, 0);
      acc[1][so] = __builtin_amdgcn_mfma_f32_16x16x32_bf16(af1.v, bfr, acc[1][so], 0, 0, 0);
    }
  }

  #pragma unroll
  for (int si = 0; si < 2; ++si)
    #pragma unroll
    for (int so = 0; so < 8; ++so)
      #pragma unroll
      for (int q = 0; q < 4; ++q){
        int il = si * 16 + kg * 4 + q;
        int o  = so * 16 + r;
        cmb[wv][il][o] = acc[si][so][q];
      }
  __syncthreads();
  for (int e = threadIdx.x; e < 4096; e += 256){
    int i = e >> 7, o = e & 127;
    float v = cmb[0][i][o] + cmb[1][i][o] + cmb[2][i][o] + cmb[3][i][o];
    float res = v > 0.f ? v : (exp2f(v * L2E) - 1.0f);
    out[(size_t)(b * 2048 + ib * 32 + i) * 128 + o] = res;
  }
}

// ---------------- launch ----------------
extern "C" void kernel_launch(void* const* d_in, const int* in_sizes, int n_in,
                              void* d_out, int out_size, void* d_ws, size_t ws_size,
                              hipStream_t stream){
  const float* x   = (const float*)d_in[0];
  const float* adj = (const float*)d_in[1];
  const float* W   = (const float*)d_in[2];
  const float* a1  = (const float*)d_in[3];
  const float* a2  = (const float*)d_in[4];
  const float* ab  = (const float*)d_in[5];
  float* out = (float*)d_out;

  // ws layout (bytes):
  //   h     f32 [16384*128]       @ 0          (8,388,608)
  //   E1    f32 [16384]           @ 8388608    (65,536)
  //   E2    f32 [16384]           @ 8454144    (65,536)
  //   denom f32 [16384]           @ 8519680    (65,536)
  //   mask  u64 [8*2048*32]       @ 8585216    (4,194,304)
  //   gT    bf16[8*128*2048]      @ 12779520   (4,194,304)
  const size_t WS_NEEDED = 16973824;
  if (ws_size < WS_NEEDED) return;  // insufficient scratch; bail (validation will flag)

  char* ws = (char*)d_ws;
  float* h     = (float*)(ws);
  float* E1    = (float*)(ws + 8388608);
  float* E2    = (float*)(ws + 8454144);
  float* denom = (float*)(ws + 8519680);
  u64*   mask  = (u64*)  (ws + 8585216);
  unsigned short* gT = (unsigned short*)(ws + 12779520);

  hipMemsetAsync(denom, 0, 16384 * sizeof(float), stream);
  k_h  <<<1024, 256, 0, stream>>>(x, W, h);
  k_sv <<<4096, 256, 0, stream>>>(h, a1, a2, ab, E1, E2);
  k_dm <<<dim3(32, 4, 8), 256, 0, stream>>>(adj, E1, E2, denom, mask);
  k_gt <<<dim3(64, 4, 8), 256, 0, stream>>>(h, denom, gT);
  k_main<<<dim3(64, 8), 256, 0, stream>>>(E1, E2, (const uint32*)mask, gT, out);
}

// Round 2
// 142.052 us; speedup vs baseline: 1.1856x; 1.1856x over previous
//
#include <hip/hip_runtime.h>
#include <stdint.h>

typedef unsigned int  uint32;
typedef unsigned long long u64;

#define L2E 1.44269504088896340736f

typedef float f32x4 __attribute__((ext_vector_type(4)));
typedef short bf16x8 __attribute__((ext_vector_type(8)));

__device__ __forceinline__ unsigned short f2bf(float f){
  uint32 u = __float_as_uint(f);
  u += 0x7fffu + ((u >> 16) & 1u);
  return (unsigned short)(u >> 16);
}

// k-permutation: k' -> j:  Q = k'>>8, p = (k'>>6)&3, l = k'&63, j = Q*256 + 4*l + p
// inverse:       j  -> k': Q = j>>8,  l = (j&255)>>2, p = j&3,  k' = Q*256 + p*64 + l

// ---------------- K1: h[row][o] = dot(x[row][:], W[o][:])  (fp32) ----------------
__global__ __launch_bounds__(256) void k_h(const float* __restrict__ x,
                                           const float* __restrict__ W,
                                           float* __restrict__ h){
  __shared__ float Wl[128 * 257];
  __shared__ float xl[16 * 256];
  const int tid = threadIdx.x;
  for (int idx = tid; idx < 8192; idx += 256){
    float4 v = ((const float4*)W)[idx];
    int o = idx >> 6, f = (idx & 63) * 4;
    float* d = &Wl[o * 257 + f];
    d[0] = v.x; d[1] = v.y; d[2] = v.z; d[3] = v.w;
  }
  const int row0 = blockIdx.x * 16;
  for (int idx = tid; idx < 1024; idx += 256){
    int r = idx >> 6, f = (idx & 63) * 4;
    float4 v = *(const float4*)(x + (size_t)(row0 + r) * 256 + f);
    *(float4*)&xl[r * 256 + f] = v;
  }
  __syncthreads();
  const int o = tid & 127, half = tid >> 7;
  float acc[8] = {0,0,0,0,0,0,0,0};
  for (int f = 0; f < 256; f += 4){
    float w0 = Wl[o*257+f], w1 = Wl[o*257+f+1], w2 = Wl[o*257+f+2], w3 = Wl[o*257+f+3];
    #pragma unroll
    for (int r = 0; r < 8; ++r){
      const float* xr = &xl[(half*8 + r) * 256 + f];
      acc[r] = fmaf(xr[0], w0, fmaf(xr[1], w1, fmaf(xr[2], w2, fmaf(xr[3], w3, acc[r]))));
    }
  }
  #pragma unroll
  for (int r = 0; r < 8; ++r)
    h[(size_t)(row0 + half*8 + r) * 128 + o] = acc[r];
}

// ---------------- K1b: E1 = (h.a1)*L2E ; E2p[k'(row)] = (h.a2 + ab)*L2E ----------------
__global__ __launch_bounds__(256) void k_sv(const float* __restrict__ h,
                                            const float* __restrict__ a1,
                                            const float* __restrict__ a2,
                                            const float* __restrict__ ab,
                                            float* __restrict__ E1,
                                            float* __restrict__ E2p){
  const int row  = blockIdx.x * 4 + (threadIdx.x >> 6);
  const int lane = threadIdx.x & 63;
  float2 v = *(const float2*)(h + (size_t)row * 128 + lane * 2);
  float p1 = v.x * a1[lane*2] + v.y * a1[lane*2+1];
  float p2 = v.x * a2[lane*2] + v.y * a2[lane*2+1];
  #pragma unroll
  for (int off = 32; off; off >>= 1){
    p1 += __shfl_down(p1, off);
    p2 += __shfl_down(p2, off);
  }
  if (lane == 0){
    E1[row] = p1 * L2E;
    int bb = row >> 11, j = row & 2047;
    int kp = (j & ~255) + (j & 3) * 64 + ((j & 255) >> 2);
    E2p[bb * 2048 + kp] = (p2 + ab[0]) * L2E;
  }
}

// ---------------- K2: denom_j = sum_i adj_ij * exp2(lrelu(.)) ; mask in k'-order ----------------
// grid (Q=8, ic=4, b=8), 4 waves/block; wave covers 256 j x 128 i rows, float4/lane.
__global__ __launch_bounds__(256) void k_dm(const float* __restrict__ adj,
                                            const float* __restrict__ E1,
                                            const float* __restrict__ E2p,
                                            float* __restrict__ denom,
                                            u64* __restrict__ mask){
  __shared__ float red[4][256];
  const int b = blockIdx.z, Q = blockIdx.x, ic = blockIdx.y;
  const int wv = threadIdx.x >> 6, lane = threadIdx.x & 63;
  const int Jbase = Q * 256;
  const int row0 = ic * 512 + wv * 128;

  const float* e1p = E1 + b * 2048 + row0;
  const float4* ap = (const float4*)(adj + (size_t)(b * 2048 + row0) * 2048 + Jbase) + lane;
  u64* mp = mask + (size_t)(b * 2048 + row0) * 32 + Q * 4;

  float e2v[4];
  #pragma unroll
  for (int p = 0; p < 4; ++p)
    e2v[p] = E2p[b * 2048 + Q * 256 + p * 64 + lane];

  float ds0 = 0.f, ds1 = 0.f, ds2 = 0.f, ds3 = 0.f;

  for (int r0 = 0; r0 < 128; r0 += 8){
    float4 av[8];
    #pragma unroll
    for (int u = 0; u < 8; ++u)
      av[u] = ap[(size_t)(r0 + u) * 512];
    #pragma unroll
    for (int u = 0; u < 8; ++u){
      const float e1 = e1p[r0 + u];
      float t0 = e1 + e2v[0]; t0 = fmaxf(t0, 0.2f * t0);
      float t1 = e1 + e2v[1]; t1 = fmaxf(t1, 0.2f * t1);
      float t2 = e1 + e2v[2]; t2 = fmaxf(t2, 0.2f * t2);
      float t3 = e1 + e2v[3]; t3 = fmaxf(t3, 0.2f * t3);
      ds0 = fmaf(av[u].x, __builtin_amdgcn_exp2f(t0), ds0);
      ds1 = fmaf(av[u].y, __builtin_amdgcn_exp2f(t1), ds1);
      ds2 = fmaf(av[u].z, __builtin_amdgcn_exp2f(t2), ds2);
      ds3 = fmaf(av[u].w, __builtin_amdgcn_exp2f(t3), ds3);
      u64 b0 = __ballot(av[u].x != 0.f);
      u64 b1 = __ballot(av[u].y != 0.f);
      u64 b2 = __ballot(av[u].z != 0.f);
      u64 b3 = __ballot(av[u].w != 0.f);
      if (lane == 0){
        ulonglong2* dst = (ulonglong2*)(mp + (size_t)(r0 + u) * 32);
        dst[0] = (ulonglong2){b0, b1};
        dst[1] = (ulonglong2){b2, b3};
      }
    }
  }
  *(float4*)&red[wv][lane * 4] = (float4){ds0, ds1, ds2, ds3};
  __syncthreads();
  const int t = threadIdx.x;
  float s = red[0][t] + red[1][t] + red[2][t] + red[3][t];
  atomicAdd(&denom[b * 2048 + Jbase + t], s);
}

// ---------------- K3: gT[b][o][k'] = bf16( h[b][j(k')][o] / denom[j(k')] ) ----------------
// grid (Q=8, o-tile=4, b=8)
__global__ __launch_bounds__(256) void k_gt(const float* __restrict__ h,
                                            const float* __restrict__ denom,
                                            unsigned short* __restrict__ gT){
  __shared__ float hl[8464];   // index: j*33 + (j>>4) + oo,  oo<32
  __shared__ float rrec[256];
  const int b = blockIdx.z, Q = blockIdx.x, o0 = blockIdx.y * 32;
  const int tid = threadIdx.x;

  rrec[tid] = 1.0f / denom[b * 2048 + Q * 256 + tid];
  __syncthreads();

  #pragma unroll
  for (int it = 0; it < 8; ++it){
    int idx = tid + it * 256;
    int j = idx >> 3, f = idx & 7;
    float4 v = *(const float4*)(h + (size_t)(b * 2048 + Q * 256 + j) * 128 + o0 + f * 4);
    float rc = rrec[j];
    int base = j * 33 + (j >> 4) + f * 4;
    hl[base + 0] = v.x * rc;
    hl[base + 1] = v.y * rc;
    hl[base + 2] = v.z * rc;
    hl[base + 3] = v.w * rc;
  }
  __syncthreads();

  #pragma unroll
  for (int it = 0; it < 8; ++it){
    int idx = tid + it * 256;
    int c = idx & 63, orow = idx >> 6;
    int o = o0 + orow;
    int p = c >> 4, lb = (c & 15) * 4;
    ushort4 u;
    {
      int jl = 4 * (lb + 0) + p; u.x = f2bf(hl[jl * 33 + (jl >> 4) + orow]);
    }
    { int jl = 4 * (lb + 1) + p; u.y = f2bf(hl[jl * 33 + (jl >> 4) + orow]); }
    { int jl = 4 * (lb + 2) + p; u.z = f2bf(hl[jl * 33 + (jl >> 4) + orow]); }
    { int jl = 4 * (lb + 3) + p; u.w = f2bf(hl[jl * 33 + (jl >> 4) + orow]); }
    *(ushort4*)(gT + (size_t)(b * 128 + o) * 2048 + Q * 256 + c * 4) = u;
  }
}

// ---------------- K4: out = ELU( A @ g ), A synthesized from E1/E2p/mask ----------------
__global__ __launch_bounds__(256) void k_main(const float* __restrict__ E1,
                                              const float* __restrict__ E2p,
                                              const uint32* __restrict__ mask32,
                                              const unsigned short* __restrict__ gT,
                                              float* __restrict__ out){
  __shared__ float cmb[4][32][129];
  const int b  = blockIdx.y;
  const int ib = blockIdx.x;
  const int wv = threadIdx.x >> 6, lane = threadIdx.x & 63;
  const int r  = lane & 15, kg = lane >> 4;
  const int gi0 = b * 2048 + ib * 32 + r;
  const float e1_0 = E1[gi0];
  const float e1_1 = E1[gi0 + 16];
  const uint32* m0 = mask32 + (size_t)gi0 * 64;
  const uint32* m1 = mask32 + (size_t)(gi0 + 16) * 64;
  const unsigned short* gbase = gT + (size_t)(b * 128) * 2048;

  f32x4 acc[2][8];
  #pragma unroll
  for (int si = 0; si < 2; ++si)
    #pragma unroll
    for (int so = 0; so < 8; ++so)
      acc[si][so] = (f32x4){0.f, 0.f, 0.f, 0.f};

  const int k0 = wv * 512, k1 = k0 + 512;
  for (int kk = k0; kk < k1; kk += 32){
    const int j0 = kk + kg * 8;
    const float4 eA = *(const float4*)(E2p + b * 2048 + j0);
    const float4 eB = *(const float4*)(E2p + b * 2048 + j0 + 4);
    const uint32 bits0 = (m0[kk >> 5] >> (kg * 8)) & 0xffu;
    const uint32 bits1 = (m1[kk >> 5] >> (kg * 8)) & 0xffu;
    float e2v[8] = {eA.x, eA.y, eA.z, eA.w, eB.x, eB.y, eB.z, eB.w};

    union { uint32 u[4]; bf16x8 v; } af0, af1;
    #pragma unroll
    for (int p = 0; p < 4; ++p){
      {
        float t0 = e1_0 + e2v[2*p];     t0 = fmaxf(t0, 0.2f * t0);
        float t1 = e1_0 + e2v[2*p+1];   t1 = fmaxf(t1, 0.2f * t1);
        float x0 = ((bits0 >> (2*p))   & 1u) ? __builtin_amdgcn_exp2f(t0) : 0.f;
        float x1 = ((bits0 >> (2*p+1)) & 1u) ? __builtin_amdgcn_exp2f(t1) : 0.f;
        uint32 u0 = __float_as_uint(x0); u0 = (u0 + 0x7fffu + ((u0 >> 16) & 1u)) >> 16;
        uint32 u1 = __float_as_uint(x1); u1 = (u1 + 0x7fffu + ((u1 >> 16) & 1u)) & 0xffff0000u;
        af0.u[p] = u0 | u1;
      }
      {
        float t0 = e1_1 + e2v[2*p];     t0 = fmaxf(t0, 0.2f * t0);
        float t1 = e1_1 + e2v[2*p+1];   t1 = fmaxf(t1, 0.2f * t1);
        float x0 = ((bits1 >> (2*p))   & 1u) ? __builtin_amdgcn_exp2f(t0) : 0.f;
        float x1 = ((bits1 >> (2*p+1)) & 1u) ? __builtin_amdgcn_exp2f(t1) : 0.f;
        uint32 u0 = __float_as_uint(x0); u0 = (u0 + 0x7fffu + ((u0 >> 16) & 1u)) >> 16;
        uint32 u1 = __float_as_uint(x1); u1 = (u1 + 0x7fffu + ((u1 >> 16) & 1u)) & 0xffff0000u;
        af1.u[p] = u0 | u1;
      }
    }
    #pragma unroll
    for (int so = 0; so < 8; ++so){
      const int o = so * 16 + r;
      bf16x8 bfr = *(const bf16x8*)(gbase + (size_t)o * 2048 + j0);
      acc[0][so] = __builtin_amdgcn_mfma_f32_16x16x32_bf16(af0.v, bfr, acc[0][so], 0, 0, 0);
      acc[1][so] = __builtin_amdgcn_mfma_f32_16x16x32_bf16(af1.v, bfr, acc[1][so], 0, 0, 0);
    }
  }

  #pragma unroll
  for (int si = 0; si < 2; ++si)
    #pragma unroll
    for (int so = 0; so < 8; ++so)
      #pragma unroll
      for (int q = 0; q < 4; ++q){
        int il = si * 16 + kg * 4 + q;
        int o  = so * 16 + r;
        cmb[wv][il][o] = acc[si][so][q];
      }
  __syncthreads();
  for (int e = threadIdx.x; e < 4096; e += 256){
    int i = e >> 7, o = e & 127;
    float v = cmb[0][i][o] + cmb[1][i][o] + cmb[2][i][o] + cmb[3][i][o];
    float res = v > 0.f ? v : (__builtin_amdgcn_exp2f(v * L2E) - 1.0f);
    out[(size_t)(b * 2048 + ib * 32 + i) * 128 + o] = res;
  }
}

// ---------------- launch ----------------
extern "C" void kernel_launch(void* const* d_in, const int* in_sizes, int n_in,
                              void* d_out, int out_size, void* d_ws, size_t ws_size,
                              hipStream_t stream){
  const float* x   = (const float*)d_in[0];
  const float* adj = (const float*)d_in[1];
  const float* W   = (const float*)d_in[2];
  const float* a1  = (const float*)d_in[3];
  const float* a2  = (const float*)d_in[4];
  const float* ab  = (const float*)d_in[5];
  float* out = (float*)d_out;

  // ws layout (bytes):
  //   h     f32 [16384*128]       @ 0          (8,388,608)
  //   E1    f32 [16384]           @ 8388608    (65,536)
  //   E2p   f32 [16384]           @ 8454144    (65,536)
  //   denom f32 [16384]           @ 8519680    (65,536)
  //   mask  u64 [8*2048*32]       @ 8585216    (4,194,304)
  //   gT    bf16[8*128*2048]      @ 12779520   (4,194,304)
  const size_t WS_NEEDED = 16973824;
  if (ws_size < WS_NEEDED) return;

  char* ws = (char*)d_ws;
  float* h     = (float*)(ws);
  float* E1    = (float*)(ws + 8388608);
  float* E2p   = (float*)(ws + 8454144);
  float* denom = (float*)(ws + 8519680);
  u64*   mask  = (u64*)  (ws + 8585216);
  unsigned short* gT = (unsigned short*)(ws + 12779520);

  hipMemsetAsync(denom, 0, 16384 * sizeof(float), stream);
  k_h  <<<1024, 256, 0, stream>>>(x, W, h);
  k_sv <<<4096, 256, 0, stream>>>(h, a1, a2, ab, E1, E2p);
  k_dm <<<dim3(8, 4, 8), 256, 0, stream>>>(adj, E1, E2p, denom, mask);
  k_gt <<<dim3(8, 4, 8), 256, 0, stream>>>(h, denom, gT);
  k_main<<<dim3(64, 8), 256, 0, stream>>>(E1, E2p, (const uint32*)mask, gT, out);
}

// Round 3
// 91.534 us; speedup vs baseline: 1.8400x; 1.5519x over previous
//
#include <hip/hip_runtime.h>
#include <stdint.h>

typedef unsigned int  uint32;
typedef unsigned long long u64;

#define L2E 1.44269504088896340736f

typedef float f32x4 __attribute__((ext_vector_type(4)));
typedef short bf16x8 __attribute__((ext_vector_type(8)));

__device__ __forceinline__ unsigned short f2bf(float f){
  uint32 u = __float_as_uint(f);
  u += 0x7fffu + ((u >> 16) & 1u);
  return (unsigned short)(u >> 16);
}

// k-permutation: k' -> j:  Q = k'>>8, p = (k'>>6)&3, l = k'&63, j = Q*256 + 4*l + p
// inverse:       j  -> k': Q = j>>8,  l = (j&255)>>2, p = j&3,  k' = Q*256 + p*64 + l

// ---------------- K1: h = x @ W^T via bf16 split-precision MFMA ----------------
// block = 64 rows x 128 o, K chunked 4 x 64. h ~= xh.Wh + xh.Wl + xl.Wh (fp32 acc)
__global__ __launch_bounds__(256) void k_h(const float* __restrict__ x,
                                           const float* __restrict__ W,
                                           float* __restrict__ h){
  __shared__ unsigned short xs[2][64][72];    // [hi/lo][row][f] pad 72
  __shared__ unsigned short wsm[2][128][72];  // [hi/lo][o][f]
  const int tid = threadIdx.x;
  const int wv = tid >> 6, lane = tid & 63;
  const int r = lane & 15, kg = lane >> 4;
  const int row0 = blockIdx.x * 64;

  f32x4 acc[8];
  #pragma unroll
  for (int of = 0; of < 8; ++of) acc[of] = (f32x4){0.f,0.f,0.f,0.f};

  for (int kc = 0; kc < 4; ++kc){
    if (kc) __syncthreads();
    // stage x chunk: 64 rows x 64 f
    #pragma unroll
    for (int it = 0; it < 4; ++it){
      int idx = tid + it * 256;
      int row = idx >> 4, f = (idx & 15) * 4;
      float4 v = *(const float4*)(x + (size_t)(row0 + row) * 256 + kc * 64 + f);
      ushort4 hi, lo;
      { unsigned short hh = f2bf(v.x); float rr = v.x - __uint_as_float(((uint32)hh)<<16); hi.x = hh; lo.x = f2bf(rr); }
      { unsigned short hh = f2bf(v.y); float rr = v.y - __uint_as_float(((uint32)hh)<<16); hi.y = hh; lo.y = f2bf(rr); }
      { unsigned short hh = f2bf(v.z); float rr = v.z - __uint_as_float(((uint32)hh)<<16); hi.z = hh; lo.z = f2bf(rr); }
      { unsigned short hh = f2bf(v.w); float rr = v.w - __uint_as_float(((uint32)hh)<<16); hi.w = hh; lo.w = f2bf(rr); }
      *(ushort4*)&xs[0][row][f] = hi;
      *(ushort4*)&xs[1][row][f] = lo;
    }
    // stage W chunk: 128 o x 64 f
    #pragma unroll
    for (int it = 0; it < 8; ++it){
      int idx = tid + it * 256;
      int o = idx >> 4, f = (idx & 15) * 4;
      float4 v = *(const float4*)(W + (size_t)o * 256 + kc * 64 + f);
      ushort4 hi, lo;
      { unsigned short hh = f2bf(v.x); float rr = v.x - __uint_as_float(((uint32)hh)<<16); hi.x = hh; lo.x = f2bf(rr); }
      { unsigned short hh = f2bf(v.y); float rr = v.y - __uint_as_float(((uint32)hh)<<16); hi.y = hh; lo.y = f2bf(rr); }
      { unsigned short hh = f2bf(v.z); float rr = v.z - __uint_as_float(((uint32)hh)<<16); hi.z = hh; lo.z = f2bf(rr); }
      { unsigned short hh = f2bf(v.w); float rr = v.w - __uint_as_float(((uint32)hh)<<16); hi.w = hh; lo.w = f2bf(rr); }
      *(ushort4*)&wsm[0][o][f] = hi;
      *(ushort4*)&wsm[1][o][f] = lo;
    }
    __syncthreads();
    #pragma unroll
    for (int kk = 0; kk < 2; ++kk){
      bf16x8 ah = *(const bf16x8*)&xs[0][wv*16 + r][kk*32 + kg*8];
      bf16x8 al = *(const bf16x8*)&xs[1][wv*16 + r][kk*32 + kg*8];
      #pragma unroll
      for (int of = 0; of < 8; ++of){
        bf16x8 bh = *(const bf16x8*)&wsm[0][of*16 + r][kk*32 + kg*8];
        bf16x8 bl = *(const bf16x8*)&wsm[1][of*16 + r][kk*32 + kg*8];
        acc[of] = __builtin_amdgcn_mfma_f32_16x16x32_bf16(ah, bh, acc[of], 0, 0, 0);
        acc[of] = __builtin_amdgcn_mfma_f32_16x16x32_bf16(ah, bl, acc[of], 0, 0, 0);
        acc[of] = __builtin_amdgcn_mfma_f32_16x16x32_bf16(al, bh, acc[of], 0, 0, 0);
      }
    }
  }
  // D: lane l reg q -> row (within 16) = kg*4+q, col = r
  #pragma unroll
  for (int of = 0; of < 8; ++of)
    #pragma unroll
    for (int q = 0; q < 4; ++q)
      h[(size_t)(row0 + wv*16 + kg*4 + q) * 128 + of*16 + r] = acc[of][q];
}

// ---------------- K1b: E1 = (h.a1)*L2E ; E2p[k'(row)] = (h.a2 + ab)*L2E ----------------
__global__ __launch_bounds__(256) void k_sv(const float* __restrict__ h,
                                            const float* __restrict__ a1,
                                            const float* __restrict__ a2,
                                            const float* __restrict__ ab,
                                            float* __restrict__ E1,
                                            float* __restrict__ E2p){
  const int row  = blockIdx.x * 4 + (threadIdx.x >> 6);
  const int lane = threadIdx.x & 63;
  float2 v = *(const float2*)(h + (size_t)row * 128 + lane * 2);
  float p1 = v.x * a1[lane*2] + v.y * a1[lane*2+1];
  float p2 = v.x * a2[lane*2] + v.y * a2[lane*2+1];
  #pragma unroll
  for (int off = 32; off; off >>= 1){
    p1 += __shfl_down(p1, off);
    p2 += __shfl_down(p2, off);
  }
  if (lane == 0){
    E1[row] = p1 * L2E;
    int bb = row >> 11, j = row & 2047;
    int kp = (j & ~255) + (j & 3) * 64 + ((j & 255) >> 2);
    E2p[bb * 2048 + kp] = (p2 + ab[0]) * L2E;
  }
}

// ---------------- K2: denom partials + mask in k'-order ----------------
// grid (Q=8, ic=8, b=8), 4 waves/block; wave covers 256 j x 64 i rows, float4/lane.
__global__ __launch_bounds__(256) void k_dm(const float* __restrict__ adj,
                                            const float* __restrict__ E1,
                                            const float* __restrict__ E2p,
                                            float* __restrict__ denomP,
                                            u64* __restrict__ mask){
  __shared__ float red[4][256];
  const int b = blockIdx.z, Q = blockIdx.x, ic = blockIdx.y;
  const int wv = threadIdx.x >> 6, lane = threadIdx.x & 63;
  const int Jbase = Q * 256;
  const int row0 = ic * 256 + wv * 64;

  const float* e1p = E1 + b * 2048 + row0;
  const float4* ap = (const float4*)(adj + (size_t)(b * 2048 + row0) * 2048 + Jbase) + lane;
  u64* mp = mask + (size_t)(b * 2048 + row0) * 32 + Q * 4;

  float e2v[4];
  #pragma unroll
  for (int p = 0; p < 4; ++p)
    e2v[p] = E2p[b * 2048 + Q * 256 + p * 64 + lane];

  float ds0 = 0.f, ds1 = 0.f, ds2 = 0.f, ds3 = 0.f;

  for (int r0 = 0; r0 < 64; r0 += 8){
    float4 av[8];
    #pragma unroll
    for (int u = 0; u < 8; ++u)
      av[u] = ap[(size_t)(r0 + u) * 512];
    #pragma unroll
    for (int u = 0; u < 8; ++u){
      const float e1 = e1p[r0 + u];
      float t0 = e1 + e2v[0]; t0 = fmaxf(t0, 0.2f * t0);
      float t1 = e1 + e2v[1]; t1 = fmaxf(t1, 0.2f * t1);
      float t2 = e1 + e2v[2]; t2 = fmaxf(t2, 0.2f * t2);
      float t3 = e1 + e2v[3]; t3 = fmaxf(t3, 0.2f * t3);
      ds0 = fmaf(av[u].x, __builtin_amdgcn_exp2f(t0), ds0);
      ds1 = fmaf(av[u].y, __builtin_amdgcn_exp2f(t1), ds1);
      ds2 = fmaf(av[u].z, __builtin_amdgcn_exp2f(t2), ds2);
      ds3 = fmaf(av[u].w, __builtin_amdgcn_exp2f(t3), ds3);
      u64 b0 = __ballot(av[u].x != 0.f);
      u64 b1 = __ballot(av[u].y != 0.f);
      u64 b2 = __ballot(av[u].z != 0.f);
      u64 b3 = __ballot(av[u].w != 0.f);
      if (lane == 0){
        ulonglong2* dst = (ulonglong2*)(mp + (size_t)(r0 + u) * 32);
        dst[0] = (ulonglong2){b0, b1};
        dst[1] = (ulonglong2){b2, b3};
      }
    }
  }
  *(float4*)&red[wv][lane * 4] = (float4){ds0, ds1, ds2, ds3};
  __syncthreads();
  const int t = threadIdx.x;
  denomP[ic * 16384 + b * 2048 + Jbase + t] = red[0][t] + red[1][t] + red[2][t] + red[3][t];
}

// ---------------- K3: gT[b][o][k'] = bf16( h[b][j(k')][o] / denom[j(k')] ) ----------------
// grid (Q=8, o-tile=4, b=8)
__global__ __launch_bounds__(256) void k_gt(const float* __restrict__ h,
                                            const float* __restrict__ denomP,
                                            unsigned short* __restrict__ gT){
  __shared__ float hl[8464];   // index: j*33 + (j>>4) + oo,  oo<32
  __shared__ float rrec[256];
  const int b = blockIdx.z, Q = blockIdx.x, o0 = blockIdx.y * 32;
  const int tid = threadIdx.x;

  {
    float d = 0.f;
    #pragma unroll
    for (int ic = 0; ic < 8; ++ic)
      d += denomP[ic * 16384 + b * 2048 + Q * 256 + tid];
    rrec[tid] = 1.0f / d;
  }
  __syncthreads();

  #pragma unroll
  for (int it = 0; it < 8; ++it){
    int idx = tid + it * 256;
    int j = idx >> 3, f = idx & 7;
    float4 v = *(const float4*)(h + (size_t)(b * 2048 + Q * 256 + j) * 128 + o0 + f * 4);
    float rc = rrec[j];
    int base = j * 33 + (j >> 4) + f * 4;
    hl[base + 0] = v.x * rc;
    hl[base + 1] = v.y * rc;
    hl[base + 2] = v.z * rc;
    hl[base + 3] = v.w * rc;
  }
  __syncthreads();

  #pragma unroll
  for (int it = 0; it < 8; ++it){
    int idx = tid + it * 256;
    int c = idx & 63, orow = idx >> 6;
    int o = o0 + orow;
    int p = c >> 4, lb = (c & 15) * 4;
    ushort4 u;
    { int jl = 4 * (lb + 0) + p; u.x = f2bf(hl[jl * 33 + (jl >> 4) + orow]); }
    { int jl = 4 * (lb + 1) + p; u.y = f2bf(hl[jl * 33 + (jl >> 4) + orow]); }
    { int jl = 4 * (lb + 2) + p; u.z = f2bf(hl[jl * 33 + (jl >> 4) + orow]); }
    { int jl = 4 * (lb + 3) + p; u.w = f2bf(hl[jl * 33 + (jl >> 4) + orow]); }
    *(ushort4*)(gT + (size_t)(b * 128 + o) * 2048 + Q * 256 + c * 4) = u;
  }
}

// ---------------- K4: out = ELU( A @ g ), A synthesized from E1/E2p/mask ----------------
__global__ __launch_bounds__(256) void k_main(const float* __restrict__ E1,
                                              const float* __restrict__ E2p,
                                              const uint32* __restrict__ mask32,
                                              const unsigned short* __restrict__ gT,
                                              float* __restrict__ out){
  __shared__ float cmb[4][32][129];
  const int b  = blockIdx.y;
  const int ib = blockIdx.x;
  const int wv = threadIdx.x >> 6, lane = threadIdx.x & 63;
  const int r  = lane & 15, kg = lane >> 4;
  const int gi0 = b * 2048 + ib * 32 + r;
  const float e1_0 = E1[gi0];
  const float e1_1 = E1[gi0 + 16];
  const uint32* m0 = mask32 + (size_t)gi0 * 64;
  const uint32* m1 = mask32 + (size_t)(gi0 + 16) * 64;
  const unsigned short* gbase = gT + (size_t)(b * 128) * 2048;

  f32x4 acc[2][8];
  #pragma unroll
  for (int si = 0; si < 2; ++si)
    #pragma unroll
    for (int so = 0; so < 8; ++so)
      acc[si][so] = (f32x4){0.f, 0.f, 0.f, 0.f};

  const int k0 = wv * 512, k1 = k0 + 512;
  for (int kk = k0; kk < k1; kk += 32){
    const int j0 = kk + kg * 8;
    const float4 eA = *(const float4*)(E2p + b * 2048 + j0);
    const float4 eB = *(const float4*)(E2p + b * 2048 + j0 + 4);
    const uint32 bits0 = (m0[kk >> 5] >> (kg * 8)) & 0xffu;
    const uint32 bits1 = (m1[kk >> 5] >> (kg * 8)) & 0xffu;
    float e2v[8] = {eA.x, eA.y, eA.z, eA.w, eB.x, eB.y, eB.z, eB.w};

    union { uint32 u[4]; bf16x8 v; } af0, af1;
    #pragma unroll
    for (int p = 0; p < 4; ++p){
      {
        float t0 = e1_0 + e2v[2*p];     t0 = fmaxf(t0, 0.2f * t0);
        float t1 = e1_0 + e2v[2*p+1];   t1 = fmaxf(t1, 0.2f * t1);
        float x0 = ((bits0 >> (2*p))   & 1u) ? __builtin_amdgcn_exp2f(t0) : 0.f;
        float x1 = ((bits0 >> (2*p+1)) & 1u) ? __builtin_amdgcn_exp2f(t1) : 0.f;
        uint32 u0 = __float_as_uint(x0); u0 = (u0 + 0x7fffu + ((u0 >> 16) & 1u)) >> 16;
        uint32 u1 = __float_as_uint(x1); u1 = (u1 + 0x7fffu + ((u1 >> 16) & 1u)) & 0xffff0000u;
        af0.u[p] = u0 | u1;
      }
      {
        float t0 = e1_1 + e2v[2*p];     t0 = fmaxf(t0, 0.2f * t0);
        float t1 = e1_1 + e2v[2*p+1];   t1 = fmaxf(t1, 0.2f * t1);
        float x0 = ((bits1 >> (2*p))   & 1u) ? __builtin_amdgcn_exp2f(t0) : 0.f;
        float x1 = ((bits1 >> (2*p+1)) & 1u) ? __builtin_amdgcn_exp2f(t1) : 0.f;
        uint32 u0 = __float_as_uint(x0); u0 = (u0 + 0x7fffu + ((u0 >> 16) & 1u)) >> 16;
        uint32 u1 = __float_as_uint(x1); u1 = (u1 + 0x7fffu + ((u1 >> 16) & 1u)) & 0xffff0000u;
        af1.u[p] = u0 | u1;
      }
    }
    #pragma unroll
    for (int so = 0; so < 8; ++so){
      const int o = so * 16 + r;
      bf16x8 bfr = *(const bf16x8*)(gbase + (size_t)o * 2048 + j0);
      acc[0][so] = __builtin_amdgcn_mfma_f32_16x16x32_bf16(af0.v, bfr, acc[0][so], 0, 0, 0);
      acc[1][so] = __builtin_amdgcn_mfma_f32_16x16x32_bf16(af1.v, bfr, acc[1][so], 0, 0, 0);
    }
  }

  #pragma unroll
  for (int si = 0; si < 2; ++si)
    #pragma unroll
    for (int so = 0; so < 8; ++so)
      #pragma unroll
      for (int q = 0; q < 4; ++q){
        int il = si * 16 + kg * 4 + q;
        int o  = so * 16 + r;
        cmb[wv][il][o] = acc[si][so][q];
      }
  __syncthreads();
  for (int e = threadIdx.x; e < 4096; e += 256){
    int i = e >> 7, o = e & 127;
    float v = cmb[0][i][o] + cmb[1][i][o] + cmb[2][i][o] + cmb[3][i][o];
    float res = v > 0.f ? v : (__builtin_amdgcn_exp2f(v * L2E) - 1.0f);
    out[(size_t)(b * 2048 + ib * 32 + i) * 128 + o] = res;
  }
}

// ---------------- launch ----------------
extern "C" void kernel_launch(void* const* d_in, const int* in_sizes, int n_in,
                              void* d_out, int out_size, void* d_ws, size_t ws_size,
                              hipStream_t stream){
  const float* x   = (const float*)d_in[0];
  const float* adj = (const float*)d_in[1];
  const float* W   = (const float*)d_in[2];
  const float* a1  = (const float*)d_in[3];
  const float* a2  = (const float*)d_in[4];
  const float* ab  = (const float*)d_in[5];
  float* out = (float*)d_out;

  // ws layout (bytes):
  //   h      f32 [16384*128]      @ 0          (8,388,608)
  //   E1     f32 [16384]          @ 8388608    (65,536)
  //   E2p    f32 [16384]          @ 8454144    (65,536)
  //   denomP f32 [8][16384]       @ 8519680    (524,288)
  //   mask   u64 [8*2048*32]      @ 9043968    (4,194,304)
  //   gT     bf16[8*128*2048]     @ 13238272   (4,194,304)
  const size_t WS_NEEDED = 17432576;
  if (ws_size < WS_NEEDED) return;

  char* ws = (char*)d_ws;
  float* h      = (float*)(ws);
  float* E1     = (float*)(ws + 8388608);
  float* E2p    = (float*)(ws + 8454144);
  float* denomP = (float*)(ws + 8519680);
  u64*   mask   = (u64*)  (ws + 9043968);
  unsigned short* gT = (unsigned short*)(ws + 13238272);

  k_h  <<<256, 256, 0, stream>>>(x, W, h);
  k_sv <<<4096, 256, 0, stream>>>(h, a1, a2, ab, E1, E2p);
  k_dm <<<dim3(8, 8, 8), 256, 0, stream>>>(adj, E1, E2p, denomP, mask);
  k_gt <<<dim3(8, 4, 8), 256, 0, stream>>>(h, denomP, gT);
  k_main<<<dim3(64, 8), 256, 0, stream>>>(E1, E2p, (const uint32*)mask, gT, out);
}

// Round 4
// 87.992 us; speedup vs baseline: 1.9141x; 1.0403x over previous
//
#include <hip/hip_runtime.h>
#include <stdint.h>

typedef unsigned int  uint32;
typedef unsigned long long u64;

#define L2E 1.44269504088896340736f

typedef float f32x4 __attribute__((ext_vector_type(4)));
typedef short bf16x8 __attribute__((ext_vector_type(8)));

__device__ __forceinline__ unsigned short f2bf(float f){
  uint32 u = __float_as_uint(f);
  u += 0x7fffu + ((u >> 16) & 1u);
  return (unsigned short)(u >> 16);
}

// k-permutation: k' -> j:  Q = k'>>8, p = (k'>>6)&3, l = k'&63, j = Q*256 + 4*l + p
// inverse:       j  -> k': Q = j>>8,  l = (j&255)>>2, p = j&3,  k' = Q*256 + p*64 + l

// ---------------- K1: h = x @ W^T (bf16 split MFMA) + fused E1/E2p epilogue ----------------
__global__ __launch_bounds__(256) void k_h(const float* __restrict__ x,
                                           const float* __restrict__ W,
                                           const float* __restrict__ a1,
                                           const float* __restrict__ a2,
                                           const float* __restrict__ ab,
                                           float* __restrict__ h,
                                           float* __restrict__ E1,
                                           float* __restrict__ E2p){
  __shared__ unsigned short xs[2][64][72];    // [hi/lo][row][f] pad 72
  __shared__ unsigned short wsm[2][128][72];  // [hi/lo][o][f]
  const int tid = threadIdx.x;
  const int wv = tid >> 6, lane = tid & 63;
  const int r = lane & 15, kg = lane >> 4;
  const int row0 = blockIdx.x * 64;

  f32x4 acc[8];
  #pragma unroll
  for (int of = 0; of < 8; ++of) acc[of] = (f32x4){0.f,0.f,0.f,0.f};

  for (int kc = 0; kc < 4; ++kc){
    if (kc) __syncthreads();
    #pragma unroll
    for (int it = 0; it < 4; ++it){
      int idx = tid + it * 256;
      int row = idx >> 4, f = (idx & 15) * 4;
      float4 v = *(const float4*)(x + (size_t)(row0 + row) * 256 + kc * 64 + f);
      ushort4 hi, lo;
      { unsigned short hh = f2bf(v.x); float rr = v.x - __uint_as_float(((uint32)hh)<<16); hi.x = hh; lo.x = f2bf(rr); }
      { unsigned short hh = f2bf(v.y); float rr = v.y - __uint_as_float(((uint32)hh)<<16); hi.y = hh; lo.y = f2bf(rr); }
      { unsigned short hh = f2bf(v.z); float rr = v.z - __uint_as_float(((uint32)hh)<<16); hi.z = hh; lo.z = f2bf(rr); }
      { unsigned short hh = f2bf(v.w); float rr = v.w - __uint_as_float(((uint32)hh)<<16); hi.w = hh; lo.w = f2bf(rr); }
      *(ushort4*)&xs[0][row][f] = hi;
      *(ushort4*)&xs[1][row][f] = lo;
    }
    #pragma unroll
    for (int it = 0; it < 8; ++it){
      int idx = tid + it * 256;
      int o = idx >> 4, f = (idx & 15) * 4;
      float4 v = *(const float4*)(W + (size_t)o * 256 + kc * 64 + f);
      ushort4 hi, lo;
      { unsigned short hh = f2bf(v.x); float rr = v.x - __uint_as_float(((uint32)hh)<<16); hi.x = hh; lo.x = f2bf(rr); }
      { unsigned short hh = f2bf(v.y); float rr = v.y - __uint_as_float(((uint32)hh)<<16); hi.y = hh; lo.y = f2bf(rr); }
      { unsigned short hh = f2bf(v.z); float rr = v.z - __uint_as_float(((uint32)hh)<<16); hi.z = hh; lo.z = f2bf(rr); }
      { unsigned short hh = f2bf(v.w); float rr = v.w - __uint_as_float(((uint32)hh)<<16); hi.w = hh; lo.w = f2bf(rr); }
      *(ushort4*)&wsm[0][o][f] = hi;
      *(ushort4*)&wsm[1][o][f] = lo;
    }
    __syncthreads();
    #pragma unroll
    for (int kk = 0; kk < 2; ++kk){
      bf16x8 ah = *(const bf16x8*)&xs[0][wv*16 + r][kk*32 + kg*8];
      bf16x8 al = *(const bf16x8*)&xs[1][wv*16 + r][kk*32 + kg*8];
      #pragma unroll
      for (int of = 0; of < 8; ++of){
        bf16x8 bh = *(const bf16x8*)&wsm[0][of*16 + r][kk*32 + kg*8];
        bf16x8 bl = *(const bf16x8*)&wsm[1][of*16 + r][kk*32 + kg*8];
        acc[of] = __builtin_amdgcn_mfma_f32_16x16x32_bf16(ah, bh, acc[of], 0, 0, 0);
        acc[of] = __builtin_amdgcn_mfma_f32_16x16x32_bf16(ah, bl, acc[of], 0, 0, 0);
        acc[of] = __builtin_amdgcn_mfma_f32_16x16x32_bf16(al, bh, acc[of], 0, 0, 0);
      }
    }
  }
  // D: lane l reg q -> row = row0 + wv*16 + kg*4 + q, col = of*16 + r
  #pragma unroll
  for (int of = 0; of < 8; ++of)
    #pragma unroll
    for (int q = 0; q < 4; ++q)
      h[(size_t)(row0 + wv*16 + kg*4 + q) * 128 + of*16 + r] = acc[of][q];

  // fused E1/E2p: reduce acc over (of, r) for each of the lane's 4 rows
  float p1[4] = {0,0,0,0}, p2[4] = {0,0,0,0};
  #pragma unroll
  for (int of = 0; of < 8; ++of){
    float w1 = a1[of*16 + r], w2 = a2[of*16 + r];
    #pragma unroll
    for (int q = 0; q < 4; ++q){
      p1[q] = fmaf(acc[of][q], w1, p1[q]);
      p2[q] = fmaf(acc[of][q], w2, p2[q]);
    }
  }
  #pragma unroll
  for (int off = 8; off; off >>= 1)
    #pragma unroll
    for (int q = 0; q < 4; ++q){
      p1[q] += __shfl_xor(p1[q], off);
      p2[q] += __shfl_xor(p2[q], off);
    }
  if (r == 0){
    float abv = ab[0];
    #pragma unroll
    for (int q = 0; q < 4; ++q){
      int row = row0 + wv*16 + kg*4 + q;
      E1[row] = p1[q] * L2E;
      int bb = row >> 11, j = row & 2047;
      int kp = (j & ~255) + (j & 3) * 64 + ((j & 255) >> 2);
      E2p[bb * 2048 + kp] = (p2[q] + abv) * L2E;
    }
  }
}

// ---------------- K2: denom partials + mask in k'-order (double-buffered prefetch) ----------------
// grid (Q=8, ic=16, b=8), 4 waves/block; wave: 32 i-rows x 256 j, float4/lane.
#define KDM_ROW(av, rr)                                                        \
  {                                                                            \
    const float e1 = e1p[rr];                                                  \
    float t0 = e1 + e2v[0]; t0 = fmaxf(t0, 0.2f * t0);                         \
    float t1 = e1 + e2v[1]; t1 = fmaxf(t1, 0.2f * t1);                         \
    float t2 = e1 + e2v[2]; t2 = fmaxf(t2, 0.2f * t2);                         \
    float t3 = e1 + e2v[3]; t3 = fmaxf(t3, 0.2f * t3);                         \
    ds0 = fmaf((av).x, __builtin_amdgcn_exp2f(t0), ds0);                       \
    ds1 = fmaf((av).y, __builtin_amdgcn_exp2f(t1), ds1);                       \
    ds2 = fmaf((av).z, __builtin_amdgcn_exp2f(t2), ds2);                       \
    ds3 = fmaf((av).w, __builtin_amdgcn_exp2f(t3), ds3);                       \
    u64 b0 = __ballot((av).x != 0.f);                                          \
    u64 b1 = __ballot((av).y != 0.f);                                          \
    u64 b2 = __ballot((av).z != 0.f);                                          \
    u64 b3 = __ballot((av).w != 0.f);                                          \
    if (lane == 0){                                                            \
      ulonglong2* dst = (ulonglong2*)(mp + (size_t)(rr) * 32);                 \
      dst[0] = (ulonglong2){b0, b1};                                           \
      dst[1] = (ulonglong2){b2, b3};                                           \
    }                                                                          \
  }

__global__ __launch_bounds__(256) void k_dm(const float* __restrict__ adj,
                                            const float* __restrict__ E1,
                                            const float* __restrict__ E2p,
                                            float* __restrict__ denomP,
                                            u64* __restrict__ mask){
  __shared__ float red[4][256];
  const int b = blockIdx.z, Q = blockIdx.x, ic = blockIdx.y;
  const int wv = threadIdx.x >> 6, lane = threadIdx.x & 63;
  const int Jbase = Q * 256;
  const int row0 = ic * 128 + wv * 32;

  const float* e1p = E1 + b * 2048 + row0;
  const float4* ap = (const float4*)(adj + (size_t)(b * 2048 + row0) * 2048 + Jbase) + lane;
  u64* mp = mask + (size_t)(b * 2048 + row0) * 32 + Q * 4;

  float e2v[4];
  #pragma unroll
  for (int p = 0; p < 4; ++p)
    e2v[p] = E2p[b * 2048 + Q * 256 + p * 64 + lane];

  float ds0 = 0.f, ds1 = 0.f, ds2 = 0.f, ds3 = 0.f;

  float4 avA[4], avB[4];
  #pragma unroll
  for (int u = 0; u < 4; ++u) avA[u] = ap[(size_t)u * 512];

  #pragma unroll
  for (int g = 0; g < 4; ++g){
    const int rA = g * 8;
    #pragma unroll
    for (int u = 0; u < 4; ++u) avB[u] = ap[(size_t)(rA + 4 + u) * 512];
    #pragma unroll
    for (int u = 0; u < 4; ++u) KDM_ROW(avA[u], rA + u)
    if (g < 3){
      #pragma unroll
      for (int u = 0; u < 4; ++u) avA[u] = ap[(size_t)(rA + 8 + u) * 512];
    }
    #pragma unroll
    for (int u = 0; u < 4; ++u) KDM_ROW(avB[u], rA + 4 + u)
  }

  *(float4*)&red[wv][lane * 4] = (float4){ds0, ds1, ds2, ds3};
  __syncthreads();
  const int t = threadIdx.x;
  denomP[ic * 16384 + b * 2048 + Jbase + t] = red[0][t] + red[1][t] + red[2][t] + red[3][t];
}

// ---------------- K3: gT[b][o][k'] = bf16( h[b][j(k')][o] / denom[j(k')] ) ----------------
// grid (Q=8, o-tile=4, b=8)
__global__ __launch_bounds__(256) void k_gt(const float* __restrict__ h,
                                            const float* __restrict__ denomP,
                                            unsigned short* __restrict__ gT){
  __shared__ float hl[8464];   // index: j*33 + (j>>4) + oo,  oo<32
  __shared__ float rrec[256];
  const int b = blockIdx.z, Q = blockIdx.x, o0 = blockIdx.y * 32;
  const int tid = threadIdx.x;

  {
    float d = 0.f;
    #pragma unroll
    for (int ic = 0; ic < 16; ++ic)
      d += denomP[ic * 16384 + b * 2048 + Q * 256 + tid];
    rrec[tid] = 1.0f / d;
  }
  __syncthreads();

  #pragma unroll
  for (int it = 0; it < 8; ++it){
    int idx = tid + it * 256;
    int j = idx >> 3, f = idx & 7;
    float4 v = *(const float4*)(h + (size_t)(b * 2048 + Q * 256 + j) * 128 + o0 + f * 4);
    float rc = rrec[j];
    int base = j * 33 + (j >> 4) + f * 4;
    hl[base + 0] = v.x * rc;
    hl[base + 1] = v.y * rc;
    hl[base + 2] = v.z * rc;
    hl[base + 3] = v.w * rc;
  }
  __syncthreads();

  #pragma unroll
  for (int it = 0; it < 8; ++it){
    int idx = tid + it * 256;
    int c = idx & 63, orow = idx >> 6;
    int o = o0 + orow;
    int p = c >> 4, lb = (c & 15) * 4;
    ushort4 u;
    { int jl = 4 * (lb + 0) + p; u.x = f2bf(hl[jl * 33 + (jl >> 4) + orow]); }
    { int jl = 4 * (lb + 1) + p; u.y = f2bf(hl[jl * 33 + (jl >> 4) + orow]); }
    { int jl = 4 * (lb + 2) + p; u.z = f2bf(hl[jl * 33 + (jl >> 4) + orow]); }
    { int jl = 4 * (lb + 3) + p; u.w = f2bf(hl[jl * 33 + (jl >> 4) + orow]); }
    *(ushort4*)(gT + (size_t)(b * 128 + o) * 2048 + Q * 256 + c * 4) = u;
  }
}

// ---------------- K4: out = ELU( A @ g ), A synthesized from E1/E2p/mask ----------------
__global__ __launch_bounds__(256) void k_main(const float* __restrict__ E1,
                                              const float* __restrict__ E2p,
                                              const uint32* __restrict__ mask32,
                                              const unsigned short* __restrict__ gT,
                                              float* __restrict__ out){
  __shared__ float cmb[4][32][129];
  const int b  = blockIdx.y;
  const int ib = blockIdx.x;
  const int wv = threadIdx.x >> 6, lane = threadIdx.x & 63;
  const int r  = lane & 15, kg = lane >> 4;
  const int gi0 = b * 2048 + ib * 32 + r;
  const float e1_0 = E1[gi0];
  const float e1_1 = E1[gi0 + 16];
  const uint32* m0 = mask32 + (size_t)gi0 * 64;
  const uint32* m1 = mask32 + (size_t)(gi0 + 16) * 64;
  const unsigned short* gbase = gT + (size_t)(b * 128) * 2048;

  f32x4 acc[2][8];
  #pragma unroll
  for (int si = 0; si < 2; ++si)
    #pragma unroll
    for (int so = 0; so < 8; ++so)
      acc[si][so] = (f32x4){0.f, 0.f, 0.f, 0.f};

  const int k0 = wv * 512, k1 = k0 + 512;
  for (int kk = k0; kk < k1; kk += 32){
    const int j0 = kk + kg * 8;
    const float4 eA = *(const float4*)(E2p + b * 2048 + j0);
    const float4 eB = *(const float4*)(E2p + b * 2048 + j0 + 4);
    const uint32 bits0 = (m0[kk >> 5] >> (kg * 8)) & 0xffu;
    const uint32 bits1 = (m1[kk >> 5] >> (kg * 8)) & 0xffu;
    float e2v[8] = {eA.x, eA.y, eA.z, eA.w, eB.x, eB.y, eB.z, eB.w};

    union { uint32 u[4]; bf16x8 v; } af0, af1;
    #pragma unroll
    for (int p = 0; p < 4; ++p){
      {
        float t0 = e1_0 + e2v[2*p];     t0 = fmaxf(t0, 0.2f * t0);
        float t1 = e1_0 + e2v[2*p+1];   t1 = fmaxf(t1, 0.2f * t1);
        float x0 = ((bits0 >> (2*p))   & 1u) ? __builtin_amdgcn_exp2f(t0) : 0.f;
        float x1 = ((bits0 >> (2*p+1)) & 1u) ? __builtin_amdgcn_exp2f(t1) : 0.f;
        uint32 u0 = __float_as_uint(x0); u0 = (u0 + 0x7fffu + ((u0 >> 16) & 1u)) >> 16;
        uint32 u1 = __float_as_uint(x1); u1 = (u1 + 0x7fffu + ((u1 >> 16) & 1u)) & 0xffff0000u;
        af0.u[p] = u0 | u1;
      }
      {
        float t0 = e1_1 + e2v[2*p];     t0 = fmaxf(t0, 0.2f * t0);
        float t1 = e1_1 + e2v[2*p+1];   t1 = fmaxf(t1, 0.2f * t1);
        float x0 = ((bits1 >> (2*p))   & 1u) ? __builtin_amdgcn_exp2f(t0) : 0.f;
        float x1 = ((bits1 >> (2*p+1)) & 1u) ? __builtin_amdgcn_exp2f(t1) : 0.f;
        uint32 u0 = __float_as_uint(x0); u0 = (u0 + 0x7fffu + ((u0 >> 16) & 1u)) >> 16;
        uint32 u1 = __float_as_uint(x1); u1 = (u1 + 0x7fffu + ((u1 >> 16) & 1u)) & 0xffff0000u;
        af1.u[p] = u0 | u1;
      }
    }
    #pragma unroll
    for (int so = 0; so < 8; ++so){
      const int o = so * 16 + r;
      bf16x8 bfr = *(const bf16x8*)(gbase + (size_t)o * 2048 + j0);
      acc[0][so] = __builtin_amdgcn_mfma_f32_16x16x32_bf16(af0.v, bfr, acc[0][so], 0, 0, 0);
      acc[1][so] = __builtin_amdgcn_mfma_f32_16x16x32_bf16(af1.v, bfr, acc[1][so], 0, 0, 0);
    }
  }

  #pragma unroll
  for (int si = 0; si < 2; ++si)
    #pragma unroll
    for (int so = 0; so < 8; ++so)
      #pragma unroll
      for (int q = 0; q < 4; ++q){
        int il = si * 16 + kg * 4 + q;
        int o  = so * 16 + r;
        cmb[wv][il][o] = acc[si][so][q];
      }
  __syncthreads();
  for (int e = threadIdx.x; e < 4096; e += 256){
    int i = e >> 7, o = e & 127;
    float v = cmb[0][i][o] + cmb[1][i][o] + cmb[2][i][o] + cmb[3][i][o];
    float res = v > 0.f ? v : (__builtin_amdgcn_exp2f(v * L2E) - 1.0f);
    out[(size_t)(b * 2048 + ib * 32 + i) * 128 + o] = res;
  }
}

// ---------------- launch ----------------
extern "C" void kernel_launch(void* const* d_in, const int* in_sizes, int n_in,
                              void* d_out, int out_size, void* d_ws, size_t ws_size,
                              hipStream_t stream){
  const float* x   = (const float*)d_in[0];
  const float* adj = (const float*)d_in[1];
  const float* W   = (const float*)d_in[2];
  const float* a1  = (const float*)d_in[3];
  const float* a2  = (const float*)d_in[4];
  const float* ab  = (const float*)d_in[5];
  float* out = (float*)d_out;

  // ws layout (bytes):
  //   h      f32 [16384*128]      @ 0          (8,388,608)
  //   E1     f32 [16384]          @ 8388608    (65,536)
  //   E2p    f32 [16384]          @ 8454144    (65,536)
  //   denomP f32 [16][16384]      @ 8519680    (1,048,576)
  //   mask   u64 [8*2048*32]      @ 9568256    (4,194,304)
  //   gT     bf16[8*128*2048]     @ 13762560   (4,194,304)
  const size_t WS_NEEDED = 17956864;
  if (ws_size < WS_NEEDED) return;

  char* ws = (char*)d_ws;
  float* h      = (float*)(ws);
  float* E1     = (float*)(ws + 8388608);
  float* E2p    = (float*)(ws + 8454144);
  float* denomP = (float*)(ws + 8519680);
  u64*   mask   = (u64*)  (ws + 9568256);
  unsigned short* gT = (unsigned short*)(ws + 13762560);

  k_h  <<<256, 256, 0, stream>>>(x, W, a1, a2, ab, h, E1, E2p);
  k_dm <<<dim3(8, 16, 8), 256, 0, stream>>>(adj, E1, E2p, denomP, mask);
  k_gt <<<dim3(8, 4, 8), 256, 0, stream>>>(h, denomP, gT);
  k_main<<<dim3(64, 8), 256, 0, stream>>>(E1, E2p, (const uint32*)mask, gT, out);
}

// Round 5
// 68.769 us; speedup vs baseline: 2.4491x; 1.2795x over previous
//
#include <hip/hip_runtime.h>
#include <stdint.h>

typedef unsigned int  uint32;
typedef unsigned long long u64;

#define L2E 1.44269504088896340736f

typedef float f32x4 __attribute__((ext_vector_type(4)));
typedef short bf16x8 __attribute__((ext_vector_type(8)));

__device__ __forceinline__ unsigned short f2bf(float f){
  uint32 u = __float_as_uint(f);
  u += 0x7fffu + ((u >> 16) & 1u);
  return (unsigned short)(u >> 16);
}

// k-permutation: k' -> j:  Q = k'>>8, p = (k'>>6)&3, l = k'&63, j = Q*256 + 4*l + p
// inverse:       j  -> k': Q = j>>8,  l = (j&255)>>2, p = j&3,  k' = Q*256 + p*64 + l
// gTp fragment layout: element (b, o, k') at
//   ((b*64 + (k'>>5))*8 + (o>>4))*512 + (((k'>>3)&3)*16 + (o&15))*8 + (k'&7)
// so a wave's MFMA B-frag load (lane l = kg*16+r) is 16B*lane contiguous (1KB).

// ---------------- K1: h = x @ W^T (bf16 split MFMA) + fused E1/E2p epilogue ----------------
__global__ __launch_bounds__(256) void k_h(const float* __restrict__ x,
                                           const float* __restrict__ W,
                                           const float* __restrict__ a1,
                                           const float* __restrict__ a2,
                                           const float* __restrict__ ab,
                                           float* __restrict__ h,
                                           float* __restrict__ E1,
                                           float* __restrict__ E2p){
  __shared__ unsigned short xs[2][64][72];    // [hi/lo][row][f] pad 72
  __shared__ unsigned short wsm[2][128][72];  // [hi/lo][o][f]
  const int tid = threadIdx.x;
  const int wv = tid >> 6, lane = tid & 63;
  const int r = lane & 15, kg = lane >> 4;
  const int row0 = blockIdx.x * 64;

  f32x4 acc[8];
  #pragma unroll
  for (int of = 0; of < 8; ++of) acc[of] = (f32x4){0.f,0.f,0.f,0.f};

  for (int kc = 0; kc < 4; ++kc){
    if (kc) __syncthreads();
    #pragma unroll
    for (int it = 0; it < 4; ++it){
      int idx = tid + it * 256;
      int row = idx >> 4, f = (idx & 15) * 4;
      float4 v = *(const float4*)(x + (size_t)(row0 + row) * 256 + kc * 64 + f);
      ushort4 hi, lo;
      { unsigned short hh = f2bf(v.x); float rr = v.x - __uint_as_float(((uint32)hh)<<16); hi.x = hh; lo.x = f2bf(rr); }
      { unsigned short hh = f2bf(v.y); float rr = v.y - __uint_as_float(((uint32)hh)<<16); hi.y = hh; lo.y = f2bf(rr); }
      { unsigned short hh = f2bf(v.z); float rr = v.z - __uint_as_float(((uint32)hh)<<16); hi.z = hh; lo.z = f2bf(rr); }
      { unsigned short hh = f2bf(v.w); float rr = v.w - __uint_as_float(((uint32)hh)<<16); hi.w = hh; lo.w = f2bf(rr); }
      *(ushort4*)&xs[0][row][f] = hi;
      *(ushort4*)&xs[1][row][f] = lo;
    }
    #pragma unroll
    for (int it = 0; it < 8; ++it){
      int idx = tid + it * 256;
      int o = idx >> 4, f = (idx & 15) * 4;
      float4 v = *(const float4*)(W + (size_t)o * 256 + kc * 64 + f);
      ushort4 hi, lo;
      { unsigned short hh = f2bf(v.x); float rr = v.x - __uint_as_float(((uint32)hh)<<16); hi.x = hh; lo.x = f2bf(rr); }
      { unsigned short hh = f2bf(v.y); float rr = v.y - __uint_as_float(((uint32)hh)<<16); hi.y = hh; lo.y = f2bf(rr); }
      { unsigned short hh = f2bf(v.z); float rr = v.z - __uint_as_float(((uint32)hh)<<16); hi.z = hh; lo.z = f2bf(rr); }
      { unsigned short hh = f2bf(v.w); float rr = v.w - __uint_as_float(((uint32)hh)<<16); hi.w = hh; lo.w = f2bf(rr); }
      *(ushort4*)&wsm[0][o][f] = hi;
      *(ushort4*)&wsm[1][o][f] = lo;
    }
    __syncthreads();
    #pragma unroll
    for (int kk = 0; kk < 2; ++kk){
      bf16x8 ah = *(const bf16x8*)&xs[0][wv*16 + r][kk*32 + kg*8];
      bf16x8 al = *(const bf16x8*)&xs[1][wv*16 + r][kk*32 + kg*8];
      #pragma unroll
      for (int of = 0; of < 8; ++of){
        bf16x8 bh = *(const bf16x8*)&wsm[0][of*16 + r][kk*32 + kg*8];
        bf16x8 bl = *(const bf16x8*)&wsm[1][of*16 + r][kk*32 + kg*8];
        acc[of] = __builtin_amdgcn_mfma_f32_16x16x32_bf16(ah, bh, acc[of], 0, 0, 0);
        acc[of] = __builtin_amdgcn_mfma_f32_16x16x32_bf16(ah, bl, acc[of], 0, 0, 0);
        acc[of] = __builtin_amdgcn_mfma_f32_16x16x32_bf16(al, bh, acc[of], 0, 0, 0);
      }
    }
  }
  // D: lane l reg q -> row = row0 + wv*16 + kg*4 + q, col = of*16 + r
  #pragma unroll
  for (int of = 0; of < 8; ++of)
    #pragma unroll
    for (int q = 0; q < 4; ++q)
      h[(size_t)(row0 + wv*16 + kg*4 + q) * 128 + of*16 + r] = acc[of][q];

  // fused E1/E2p: reduce acc over (of, r) for each of the lane's 4 rows
  float p1[4] = {0,0,0,0}, p2[4] = {0,0,0,0};
  #pragma unroll
  for (int of = 0; of < 8; ++of){
    float w1 = a1[of*16 + r], w2 = a2[of*16 + r];
    #pragma unroll
    for (int q = 0; q < 4; ++q){
      p1[q] = fmaf(acc[of][q], w1, p1[q]);
      p2[q] = fmaf(acc[of][q], w2, p2[q]);
    }
  }
  #pragma unroll
  for (int off = 8; off; off >>= 1)
    #pragma unroll
    for (int q = 0; q < 4; ++q){
      p1[q] += __shfl_xor(p1[q], off);
      p2[q] += __shfl_xor(p2[q], off);
    }
  if (r == 0){
    float abv = ab[0];
    #pragma unroll
    for (int q = 0; q < 4; ++q){
      int row = row0 + wv*16 + kg*4 + q;
      E1[row] = p1[q] * L2E;
      int bb = row >> 11, j = row & 2047;
      int kp = (j & ~255) + (j & 3) * 64 + ((j & 255) >> 2);
      E2p[bb * 2048 + kp] = (p2[q] + abv) * L2E;
    }
  }
}

// ---------------- K2: denom partials + mask in k'-order (double-buffered prefetch) ----------------
#define KDM_ROW(av, rr)                                                        \
  {                                                                            \
    const float e1 = e1p[rr];                                                  \
    float t0 = e1 + e2v[0]; t0 = fmaxf(t0, 0.2f * t0);                         \
    float t1 = e1 + e2v[1]; t1 = fmaxf(t1, 0.2f * t1);                         \
    float t2 = e1 + e2v[2]; t2 = fmaxf(t2, 0.2f * t2);                         \
    float t3 = e1 + e2v[3]; t3 = fmaxf(t3, 0.2f * t3);                         \
    ds0 = fmaf((av).x, __builtin_amdgcn_exp2f(t0), ds0);                       \
    ds1 = fmaf((av).y, __builtin_amdgcn_exp2f(t1), ds1);                       \
    ds2 = fmaf((av).z, __builtin_amdgcn_exp2f(t2), ds2);                       \
    ds3 = fmaf((av).w, __builtin_amdgcn_exp2f(t3), ds3);                       \
    u64 b0 = __ballot((av).x != 0.f);                                          \
    u64 b1 = __ballot((av).y != 0.f);                                          \
    u64 b2 = __ballot((av).z != 0.f);                                          \
    u64 b3 = __ballot((av).w != 0.f);                                          \
    if (lane == 0){                                                            \
      ulonglong2* dst = (ulonglong2*)(mp + (size_t)(rr) * 32);                 \
      dst[0] = (ulonglong2){b0, b1};                                           \
      dst[1] = (ulonglong2){b2, b3};                                           \
    }                                                                          \
  }

__global__ __launch_bounds__(256) void k_dm(const float* __restrict__ adj,
                                            const float* __restrict__ E1,
                                            const float* __restrict__ E2p,
                                            float* __restrict__ denomP,
                                            u64* __restrict__ mask){
  __shared__ float red[4][256];
  const int b = blockIdx.z, Q = blockIdx.x, ic = blockIdx.y;
  const int wv = threadIdx.x >> 6, lane = threadIdx.x & 63;
  const int Jbase = Q * 256;
  const int row0 = ic * 128 + wv * 32;

  const float* e1p = E1 + b * 2048 + row0;
  const float4* ap = (const float4*)(adj + (size_t)(b * 2048 + row0) * 2048 + Jbase) + lane;
  u64* mp = mask + (size_t)(b * 2048 + row0) * 32 + Q * 4;

  float e2v[4];
  #pragma unroll
  for (int p = 0; p < 4; ++p)
    e2v[p] = E2p[b * 2048 + Q * 256 + p * 64 + lane];

  float ds0 = 0.f, ds1 = 0.f, ds2 = 0.f, ds3 = 0.f;

  float4 avA[4], avB[4];
  #pragma unroll
  for (int u = 0; u < 4; ++u) avA[u] = ap[(size_t)u * 512];

  #pragma unroll
  for (int g = 0; g < 4; ++g){
    const int rA = g * 8;
    #pragma unroll
    for (int u = 0; u < 4; ++u) avB[u] = ap[(size_t)(rA + 4 + u) * 512];
    #pragma unroll
    for (int u = 0; u < 4; ++u) KDM_ROW(avA[u], rA + u)
    if (g < 3){
      #pragma unroll
      for (int u = 0; u < 4; ++u) avA[u] = ap[(size_t)(rA + 8 + u) * 512];
    }
    #pragma unroll
    for (int u = 0; u < 4; ++u) KDM_ROW(avB[u], rA + 4 + u)
  }

  *(float4*)&red[wv][lane * 4] = (float4){ds0, ds1, ds2, ds3};
  __syncthreads();
  const int t = threadIdx.x;
  denomP[ic * 16384 + b * 2048 + Jbase + t] = red[0][t] + red[1][t] + red[2][t] + red[3][t];
}

// ---------------- K3: gTp[frag-order] = bf16( h[b][j(k')][o] / denom[j(k')] ) ----------------
// grid (Q=8, ot=4, b=8); Q covers k' = Q*256..+255 (kblk Q*8..Q*8+7), ot covers o = ot*32..+31
__global__ __launch_bounds__(256) void k_gt(const float* __restrict__ h,
                                            const float* __restrict__ denomP,
                                            unsigned short* __restrict__ gTp){
  __shared__ float hl[8464];   // index: j*33 + (j>>4) + oo,  oo<32 (local node order)
  __shared__ float rrec[256];
  const int b = blockIdx.z, Q = blockIdx.x, ot = blockIdx.y;
  const int o0 = ot * 32;
  const int tid = threadIdx.x;

  {
    float d = 0.f;
    #pragma unroll
    for (int ic = 0; ic < 16; ++ic)
      d += denomP[ic * 16384 + b * 2048 + Q * 256 + tid];
    rrec[tid] = 1.0f / d;
  }
  __syncthreads();

  #pragma unroll
  for (int it = 0; it < 8; ++it){
    int idx = tid + it * 256;
    int j = idx >> 3, f = idx & 7;
    float4 v = *(const float4*)(h + (size_t)(b * 2048 + Q * 256 + j) * 128 + o0 + f * 4);
    float rc = rrec[j];
    int base = j * 33 + (j >> 4) + f * 4;
    hl[base + 0] = v.x * rc;
    hl[base + 1] = v.y * rc;
    hl[base + 2] = v.z * rc;
    hl[base + 3] = v.w * rc;
  }
  __syncthreads();

  // write in MFMA fragment order, coalesced 1KB per 128 threads
  const int u  = tid & 127;
  const int fh = tid >> 7;          // which of 2 fragments this pass
  const int lane = u >> 1;          // 0..63
  const int e0 = (u & 1) * 4;       // 0 or 4
  const int orow_r = lane & 15;
  const int kgrp = lane >> 4;       // 0..3
  #pragma unroll
  for (int it = 0; it < 8; ++it){
    int f  = it * 2 + fh;           // 0..15
    int kb = f >> 1, sl = f & 1;    // kblk-local 0..7, so-local 0..1
    int orow = sl * 16 + orow_r;
    int klb = kb * 32 + kgrp * 8 + e0;   // k'-local base (4 consecutive)
    ushort4 uu;
    { int kl = klb + 0; int jl = 4 * (kl & 63) + (kl >> 6); uu.x = f2bf(hl[jl * 33 + (jl >> 4) + orow]); }
    { int kl = klb + 1; int jl = 4 * (kl & 63) + (kl >> 6); uu.y = f2bf(hl[jl * 33 + (jl >> 4) + orow]); }
    { int kl = klb + 2; int jl = 4 * (kl & 63) + (kl >> 6); uu.z = f2bf(hl[jl * 33 + (jl >> 4) + orow]); }
    { int kl = klb + 3; int jl = 4 * (kl & 63) + (kl >> 6); uu.w = f2bf(hl[jl * 33 + (jl >> 4) + orow]); }
    size_t dst = ((size_t)((b * 64 + Q * 8 + kb) * 8 + (ot * 2 + sl))) * 512 + lane * 8 + e0;
    *(ushort4*)(gTp + dst) = uu;
  }
}

// ---------------- K4: out = ELU( A @ g ), A synthesized, B coalesced frag loads ----------------
__global__ __launch_bounds__(256) void k_main(const float* __restrict__ E1,
                                              const float* __restrict__ E2p,
                                              const uint32* __restrict__ mask32,
                                              const unsigned short* __restrict__ gTp,
                                              float* __restrict__ out){
  __shared__ float cmb[4][32][129];
  const int b  = blockIdx.y;
  const int ib = blockIdx.x;
  const int wv = threadIdx.x >> 6, lane = threadIdx.x & 63;
  const int r  = lane & 15, kg = lane >> 4;
  const int gi0 = b * 2048 + ib * 32 + r;
  const float e1_0 = E1[gi0];
  const float e1_1 = E1[gi0 + 16];
  const uint32* m0 = mask32 + (size_t)gi0 * 64;
  const uint32* m1 = mask32 + (size_t)(gi0 + 16) * 64;

  f32x4 acc[2][8];
  #pragma unroll
  for (int si = 0; si < 2; ++si)
    #pragma unroll
    for (int so = 0; so < 8; ++so)
      acc[si][so] = (f32x4){0.f, 0.f, 0.f, 0.f};

  const int k0 = wv * 512, k1 = k0 + 512;
  for (int kk = k0; kk < k1; kk += 32){
    const int j0 = kk + kg * 8;
    const float4 eA = *(const float4*)(E2p + b * 2048 + j0);
    const float4 eB = *(const float4*)(E2p + b * 2048 + j0 + 4);
    const uint32 bits0 = (m0[kk >> 5] >> (kg * 8)) & 0xffu;
    const uint32 bits1 = (m1[kk >> 5] >> (kg * 8)) & 0xffu;
    float e2v[8] = {eA.x, eA.y, eA.z, eA.w, eB.x, eB.y, eB.z, eB.w};

    union { uint32 u[4]; bf16x8 v; } af0, af1;
    #pragma unroll
    for (int p = 0; p < 4; ++p){
      {
        float t0 = e1_0 + e2v[2*p];     t0 = fmaxf(t0, 0.2f * t0);
        float t1 = e1_0 + e2v[2*p+1];   t1 = fmaxf(t1, 0.2f * t1);
        float x0 = ((bits0 >> (2*p))   & 1u) ? __builtin_amdgcn_exp2f(t0) : 0.f;
        float x1 = ((bits0 >> (2*p+1)) & 1u) ? __builtin_amdgcn_exp2f(t1) : 0.f;
        uint32 u0 = __float_as_uint(x0); u0 = (u0 + 0x7fffu + ((u0 >> 16) & 1u)) >> 16;
        uint32 u1 = __float_as_uint(x1); u1 = (u1 + 0x7fffu + ((u1 >> 16) & 1u)) & 0xffff0000u;
        af0.u[p] = u0 | u1;
      }
      {
        float t0 = e1_1 + e2v[2*p];     t0 = fmaxf(t0, 0.2f * t0);
        float t1 = e1_1 + e2v[2*p+1];   t1 = fmaxf(t1, 0.2f * t1);
        float x0 = ((bits1 >> (2*p))   & 1u) ? __builtin_amdgcn_exp2f(t0) : 0.f;
        float x1 = ((bits1 >> (2*p+1)) & 1u) ? __builtin_amdgcn_exp2f(t1) : 0.f;
        uint32 u0 = __float_as_uint(x0); u0 = (u0 + 0x7fffu + ((u0 >> 16) & 1u)) >> 16;
        uint32 u1 = __float_as_uint(x1); u1 = (u1 + 0x7fffu + ((u1 >> 16) & 1u)) & 0xffff0000u;
        af1.u[p] = u0 | u1;
      }
    }
    // coalesced fragment loads: 1KB per wave per so
    const unsigned short* gk = gTp + ((size_t)(b * 64 + (kk >> 5)) * 8) * 512 + lane * 8;
    #pragma unroll
    for (int so = 0; so < 8; ++so){
      bf16x8 bfr = *(const bf16x8*)(gk + so * 512);
      acc[0][so] = __builtin_amdgcn_mfma_f32_16x16x32_bf16(af0.v, bfr, acc[0][so], 0, 0, 0);
      acc[1][so] = __builtin_amdgcn_mfma_f32_16x16x32_bf16(af1.v, bfr, acc[1][so], 0, 0, 0);
    }
  }

  #pragma unroll
  for (int si = 0; si < 2; ++si)
    #pragma unroll
    for (int so = 0; so < 8; ++so)
      #pragma unroll
      for (int q = 0; q < 4; ++q){
        int il = si * 16 + kg * 4 + q;
        int o  = so * 16 + r;
        cmb[wv][il][o] = acc[si][so][q];
      }
  __syncthreads();
  for (int e = threadIdx.x; e < 4096; e += 256){
    int i = e >> 7, o = e & 127;
    float v = cmb[0][i][o] + cmb[1][i][o] + cmb[2][i][o] + cmb[3][i][o];
    float res = v > 0.f ? v : (__builtin_amdgcn_exp2f(v * L2E) - 1.0f);
    out[(size_t)(b * 2048 + ib * 32 + i) * 128 + o] = res;
  }
}

// ---------------- launch ----------------
extern "C" void kernel_launch(void* const* d_in, const int* in_sizes, int n_in,
                              void* d_out, int out_size, void* d_ws, size_t ws_size,
                              hipStream_t stream){
  const float* x   = (const float*)d_in[0];
  const float* adj = (const float*)d_in[1];
  const float* W   = (const float*)d_in[2];
  const float* a1  = (const float*)d_in[3];
  const float* a2  = (const float*)d_in[4];
  const float* ab  = (const float*)d_in[5];
  float* out = (float*)d_out;

  // ws layout (bytes):
  //   h      f32 [16384*128]      @ 0          (8,388,608)
  //   E1     f32 [16384]          @ 8388608    (65,536)
  //   E2p    f32 [16384]          @ 8454144    (65,536)
  //   denomP f32 [16][16384]      @ 8519680    (1,048,576)
  //   mask   u64 [8*2048*32]      @ 9568256    (4,194,304)
  //   gTp    bf16[8*64*8*512]     @ 13762560   (4,194,304)
  const size_t WS_NEEDED = 17956864;
  if (ws_size < WS_NEEDED) return;

  char* ws = (char*)d_ws;
  float* h      = (float*)(ws);
  float* E1     = (float*)(ws + 8388608);
  float* E2p    = (float*)(ws + 8454144);
  float* denomP = (float*)(ws + 8519680);
  u64*   mask   = (u64*)  (ws + 9568256);
  unsigned short* gTp = (unsigned short*)(ws + 13762560);

  k_h  <<<256, 256, 0, stream>>>(x, W, a1, a2, ab, h, E1, E2p);
  k_dm <<<dim3(8, 16, 8), 256, 0, stream>>>(adj, E1, E2p, denomP, mask);
  k_gt <<<dim3(8, 4, 8), 256, 0, stream>>>(h, denomP, gTp);
  k_main<<<dim3(64, 8), 256, 0, stream>>>(E1, E2p, (const uint32*)mask, gTp, out);
}